// Round 13
// baseline (144.276 us; speedup 1.0000x reference)
//
#include <hip/hip_runtime.h>
#include <hip/hip_fp16.h>
#include <cfloat>
#include <math.h>

// Problem constants (fixed by the reference)
#define DIM    256
#define N_TOK  8192
#define N_E    8192
#define NSEG   1024         // 8-col groups per row
// Margin on d = ||e||^2 - 2*dot (bf16 approx pass, fp16-quantized group mins).
// Failure needs Dd(true)-Dd(approx-winner) + 2*quant > margin on a specific
// per-row pair: dot-err diff ~4.3sigma*6.8e-4 ~2.9e-3, fp16 quant 2*1e-3.
// 0.012 ~ 2.4x that. (Passed rounds 7-12; 0.016 and 0.008 also passed.)
#define MARGIN 0.012f

typedef __attribute__((ext_vector_type(8))) short bf16x8;
typedef __attribute__((ext_vector_type(4))) float f32x4;
typedef __attribute__((ext_vector_type(8))) unsigned short ushort8;

__device__ __forceinline__ unsigned short f2bf(float f) {      // RNE float->bf16
    unsigned u = __float_as_uint(f);
    unsigned r = u + 0x7fff + ((u >> 16) & 1);
    return (unsigned short)(r >> 16);
}
__device__ __forceinline__ unsigned fkey(float f) {            // monotone f32->u32
    unsigned u = __float_as_uint(f);
    return (u & 0x80000000u) ? ~u : (u | 0x80000000u);
}
__device__ __forceinline__ unsigned short f2h(float f) {       // RNE float->fp16 bits
    const __half h = __float2half(f);
    return *(const unsigned short*)&h;
}
__device__ __forceinline__ float h2f(unsigned short u) {
    __half_raw r; r.x = u;
    return __half2float((__half)r);
}

// ---------------------------------------------------------------------------
// K1: row-wise L2 normalize for BOTH inputs in one launch.
//  - z rows   -> zn fp32 (d_out scratch) + zb bf16 PLAIN row-major (the LDS
//    staging swizzle is applied via per-lane global addresses in mfma_dist).
//  - emb rows -> en fp32 + esw bf16 swizzled into exact MFMA A-fragment order
//    (frag16=row>>4, kc: 512 ushorts at (frag16*8+kc)*512; within:
//    ((k>>3&3)*16 + (row&15))*8 + (k&7)) + e2.
// ---------------------------------------------------------------------------
__global__ __launch_bounds__(256) void l2norm_all(const float* __restrict__ z,
                                                  const float* __restrict__ emb,
                                                  float* __restrict__ zn,
                                                  unsigned short* __restrict__ zb,
                                                  float* __restrict__ en,
                                                  unsigned short* __restrict__ esw,
                                                  float* __restrict__ e2) {
    const int lane = threadIdx.x & 63;
    const bool isE = blockIdx.x < (N_E / 4);
    const int row = (isE ? blockIdx.x : blockIdx.x - N_E / 4) * 4 + (threadIdx.x >> 6);
    const float* in = isE ? emb : z;
    float* out = isE ? en : zn;
    const float4 v = *(const float4*)(in + row * DIM + lane * 4);
    float s = v.x * v.x + v.y * v.y + v.z * v.z + v.w * v.w;
#pragma unroll
    for (int off = 1; off < 64; off <<= 1) s += __shfl_xor(s, off, 64);
    const float inv = 1.0f / fmaxf(sqrtf(s), 1e-12f);
    const float4 o = make_float4(v.x * inv, v.y * inv, v.z * inv, v.w * inv);
    *(float4*)(out + row * DIM + lane * 4) = o;
    ushort4 ob; ob.x = f2bf(o.x); ob.y = f2bf(o.y); ob.z = f2bf(o.z); ob.w = f2bf(o.w);
    const int k0 = lane * 4;
    if (isE) {
        const size_t sidx = ((size_t)((row >> 4) * 8 + (k0 >> 5)) * 64
                             + ((k0 >> 3) & 3) * 16 + (row & 15)) * 8 + (k0 & 7);
        *(ushort4*)(esw + sidx) = ob;
        float q = o.x * o.x + o.y * o.y + o.z * o.z + o.w * o.w;
#pragma unroll
        for (int off = 1; off < 64; off <<= 1) q += __shfl_xor(q, off, 64);
        if (lane == 0) e2[row] = q;
    } else {
        *(ushort4*)(zb + (size_t)row * DIM + k0) = ob;
    }
}

// ---------------------------------------------------------------------------
// K2: bf16 MFMA distance pass — R11 configuration (best measured: 51.3 us,
// MfmaUtil 26.5%, 0 bank conflicts). 128x128 tile, hybrid feed, BK=64
// double-buffered z staging, 4 K-loop barriers/block.
//  - z rows: As[2][128x8 slots] (16 KB/buffer); XOR slot swizzle baked into
//    per-lane global addresses of global_load_lds; fragment ds_read_b128
//    conflict-free. Stage p+1 has 2 kc of MFMA in flight before its drain.
//  - codes: direct from fragment-order global buffer, 2-kc-deep register
//    prefetch.
// Epilogue: per (row, 8-col group) min -> fp16 segMh[row][1024]; sm aliases As.
// ---------------------------------------------------------------------------
__global__ __launch_bounds__(256, 2) void mfma_dist(const unsigned short* __restrict__ zb,
                                                    const unsigned short* __restrict__ esw,
                                                    const float* __restrict__ e2,
                                                    unsigned short* __restrict__ segMh) {
    __shared__ __align__(16) unsigned short As[2][128 * 64];   // 2 x 16 KB z chunk-pair
    float* sm = reinterpret_cast<float*>(As);                  // aliased epilogue [16][128]

    const int tid  = threadIdx.x;
    const int lane = tid & 63;
    const int wave = tid >> 6;
    const int wm = wave & 1, wn = wave >> 1;
    const int row0 = (blockIdx.x & 63) * 128;
    const int col0 = (blockIdx.x >> 6) * 128;
    const int fr = lane & 15, q = lane >> 4;

    f32x4 acc[4][4];
#pragma unroll
    for (int ci = 0; ci < 4; ci++)
#pragma unroll
        for (int zi = 0; zi < 4; zi++) acc[ci][zi] = (f32x4){0.f, 0.f, 0.f, 0.f};

    // Code fragments: frag16 group aBase+i, address = frag*4096 + kc*512 + lane*8
    const int aBase = (col0 >> 4) + wn * 4;
    auto la = [&](int i, int kc) {
        return *(const bf16x8*)(esw + (size_t)(aBase + i) * 4096 + kc * 512 + lane * 8);
    };
    // z staging, pair p (k in [p*64, p*64+64)): wave stages rows wave*32..+31,
    // 4 instrs of 1 KB; lane -> row lane>>3 of the 8-row slab, slot lane&7;
    // global chunk fetched = p*8 + (slot ^ (r&7)).
    const int cxor = (lane & 7) ^ ((lane >> 3) & 7);            // const per lane
    const unsigned short* gZ = zb + (size_t)(row0 + wave * 32 + (lane >> 3)) * DIM + cxor * 8;
    auto stage = [&](int buf, int p) {
#pragma unroll
        for (int j = 0; j < 4; j++) {
            __builtin_amdgcn_global_load_lds(
                (const __attribute__((address_space(1))) unsigned int*)(gZ + (size_t)j * 8 * DIM + p * 64),
                (__attribute__((address_space(3))) unsigned int*)&As[buf][(wave * 32 + j * 8) * 64],
                16, 0, 0);
        }
    };
    // z fragment from LDS: kc = 2p+h, logical chunk h*4+q, slot ^= (r&7).
    auto lz = [&](int buf, int i, int h) {
        const int r = wm * 64 + i * 16 + fr;
        const int slot = (h * 4 + q) ^ (fr & 7);
        return *(const bf16x8*)&As[buf][r * 64 + slot * 8];
    };

    bf16x8 ca[8][4];
#pragma unroll
    for (int i = 0; i < 4; i++) { ca[0][i] = la(i, 0); ca[1][i] = la(i, 1); }
    stage(0, 0);

#pragma unroll
    for (int p = 0; p < 4; p++) {
        __syncthreads();                 // drains stage(p) (2 kc of compute in flight)
        if (p < 3) stage((p + 1) & 1, p + 1);
#pragma unroll
        for (int h = 0; h < 2; h++) {
            const int kc = 2 * p + h;
            if (kc + 2 < 8) {
#pragma unroll
                for (int i = 0; i < 4; i++) ca[kc + 2][i] = la(i, kc + 2);
            }
            bf16x8 zfr[4];
#pragma unroll
            for (int i = 0; i < 4; i++) zfr[i] = lz(p & 1, i, h);
#pragma unroll
            for (int ci = 0; ci < 4; ci++)
#pragma unroll
                for (int zi = 0; zi < 4; zi++)
                    acc[ci][zi] = __builtin_amdgcn_mfma_f32_16x16x32_bf16(ca[kc][ci], zfr[zi], acc[ci][zi], 0, 0, 0);
        }
    }

    // Epilogue. C/D: m (code) = (lane>>4)*4 + reg, n (z row) = lane&15.
    float4 e2q[4];
#pragma unroll
    for (int ci = 0; ci < 4; ci++)
        e2q[ci] = *(const float4*)&e2[col0 + wn * 64 + ci * 16 + q * 4];
    __syncthreads();   // all As reads done; safe to reuse as sm
#pragma unroll
    for (int ci = 0; ci < 4; ci++) {
#pragma unroll
        for (int zi = 0; zi < 4; zi++) {
            const float t0 = fmaf(-2.0f, acc[ci][zi][0], e2q[ci].x);
            const float t1 = fmaf(-2.0f, acc[ci][zi][1], e2q[ci].y);
            const float t2 = fmaf(-2.0f, acc[ci][zi][2], e2q[ci].z);
            const float t3 = fmaf(-2.0f, acc[ci][zi][3], e2q[ci].w);
            float mm = fminf(fminf(t0, t1), fminf(t2, t3));   // min over 4 codes (regs)
            mm = fminf(mm, __shfl_xor(mm, 16, 64));           // pair quads: 8-code min
            // q==0 holds codes 0..7 min; q==2 holds codes 8..15 min
            if (q == 0) sm[(wn * 8 + ci * 2 + 0) * 128 + wm * 64 + zi * 16 + fr] = mm;
            if (q == 2) sm[(wn * 8 + ci * 2 + 1) * 128 + wm * 64 + zi * 16 + fr] = mm;
        }
    }
    __syncthreads();
    // Store 16 segs x 128 rows as fp16, coalesced: thread t -> row t&127,
    // 8 consecutive segs (part = t>>7).
    {
        const int rl = tid & 127, part = tid >> 7;
        ushort8 o8;
#pragma unroll
        for (int j = 0; j < 8; j++) o8[j] = f2h(sm[(part * 8 + j) * 128 + rl]);
        *(ushort8*)&segMh[(size_t)(row0 + rl) * NSEG + (col0 >> 3) + part * 8] = o8;
    }
}

// ---------------------------------------------------------------------------
// K3 (fused select+rescore+gather): one BLOCK (4 waves) per row, ZERO global
// atomics. vs the wave-per-row version: 4x the parallelism (8192 blocks) and
// the flagged groups are rescored in PARALLEL across the 4 waves instead of
// serially bit-walked by one wave.
//  1. thread t loads groups 4t..4t+3 (2 KB coalesced); block-reduce min ->
//     threshold (LDS)
//  2. each wave ballot-compacts its flagged groups into an LDS list (LDS
//     atomic for the base; list order irrelevant — the packed key includes
//     the column, so min-of-keys gives the lowest-index tie-break)
//  3. wave w rescores entries w, w+4, ... exactly in fp32 (16 lanes split
//     the 256-dim dot, 4 cols per pass); per-wave packed min -> LDS ->
//     wave 0 merges
//  4. wave 0 gathers en[idx] -> z_q, loss partial to pl[row], index out.
// ---------------------------------------------------------------------------
__global__ __launch_bounds__(256) void select_rescore(const unsigned short* __restrict__ segMh,
                                                      const float* __restrict__ en,
                                                      const float* __restrict__ e2,
                                                      float* zq,        // d_out: z_norm in / z_q out
                                                      float* out_base,  // d_out
                                                      float* __restrict__ pl) {
    __shared__ float s_wmin[4];
    __shared__ unsigned long long s_pk[4];
    __shared__ unsigned short s_list[NSEG];
    __shared__ int s_cnt;

    const int tid  = threadIdx.x;
    const int lane = tid & 63;
    const int wave = tid >> 6;
    const int row  = blockIdx.x;

    // Phase 1: per-thread 4 group mins (2 KB coalesced across the block).
    const ushort4 u = *(const ushort4*)(segMh + (size_t)row * NSEG + tid * 4);
    const float vv[4] = {h2f(u.x), h2f(u.y), h2f(u.z), h2f(u.w)};
    float m = fminf(fminf(vv[0], vv[1]), fminf(vv[2], vv[3]));
#pragma unroll
    for (int off = 1; off < 64; off <<= 1) m = fminf(m, __shfl_xor(m, off, 64));
    if (lane == 0) s_wmin[wave] = m;
    if (tid == 0) s_cnt = 0;
    __syncthreads();
    const float thr = fminf(fminf(s_wmin[0], s_wmin[1]),
                            fminf(s_wmin[2], s_wmin[3])) + MARGIN;

    // Phase 2: ballot-compact flagged groups into the LDS list.
#pragma unroll
    for (int j = 0; j < 4; j++) {
        const bool fl = vv[j] <= thr;
        const unsigned long long bal = __ballot(fl);
        const int cnt = __popcll(bal);
        int base = 0;
        if (lane == 0 && cnt) base = atomicAdd(&s_cnt, cnt);
        base = __shfl(base, 0, 64);
        if (fl) {
            const int pos = base + __popcll(bal & ((1ull << lane) - 1));
            s_list[pos] = (unsigned short)(tid * 4 + j);
        }
    }
    __syncthreads();
    const int F = s_cnt;

    // Phase 3: parallel exact rescore; wave w takes entries w, w+4, ...
    const int q = lane >> 4, f = lane & 15;
    const float4* zp = (const float4*)(zq + (size_t)row * DIM);
    float4 z4[4];
#pragma unroll
    for (int j = 0; j < 4; j++) z4[j] = zp[j * 16 + f];
    unsigned long long pk = ~0ull;
    for (int e = wave; e < F; e += 4) {
        const int seg = s_list[e];
#pragma unroll
        for (int g = 0; g < 2; g++) {
            const int col = seg * 8 + g * 4 + q;
            const float4* ep = (const float4*)(en + (size_t)col * DIM);
            float s = 0.f;
#pragma unroll
            for (int jj = 0; jj < 4; jj++) {
                const float4 ev = ep[jj * 16 + f];
                s = fmaf(z4[jj].x, ev.x, s); s = fmaf(z4[jj].y, ev.y, s);
                s = fmaf(z4[jj].z, ev.z, s); s = fmaf(z4[jj].w, ev.w, s);
            }
#pragma unroll
            for (int off = 1; off < 16; off <<= 1) s += __shfl_xor(s, off, 64);
            const float d = fmaf(-2.0f, s, e2[col]);
            const unsigned long long key =
                ((unsigned long long)fkey(d) << 32) | (unsigned)col;
            if (key < pk) pk = key;
        }
    }
#pragma unroll
    for (int off = 16; off < 64; off <<= 1) {               // merge the 4 quads
        const unsigned long long o = __shfl_xor(pk, off, 64);
        if (o < pk) pk = o;
    }
    if (lane == 0) s_pk[wave] = pk;
    __syncthreads();

    // Phase 4: wave 0 merges, gathers z_q, writes loss partial + index.
    if (wave == 0) {
        unsigned long long p2 = (lane < 4) ? s_pk[lane] : ~0ull;
#pragma unroll
        for (int off = 1; off < 4; off <<= 1) {
            const unsigned long long o = __shfl_xor(p2, off, 64);
            if (o < p2) p2 = o;
        }
        p2 = __shfl(p2, 0, 64);
        const int i = (int)(p2 & 0xffffffffu);
        const float4 qv = *(const float4*)(en + (size_t)i * DIM + lane * 4);
        const float4 zv = *(const float4*)(zq + (size_t)row * DIM + lane * 4);
        const float dx = qv.x - zv.x, dy = qv.y - zv.y;
        const float dz = qv.z - zv.z, dw = qv.w - zv.w;
        float s = dx * dx + dy * dy + dz * dz + dw * dw;
        *(float4*)(zq + (size_t)row * DIM + lane * 4) = qv;
#pragma unroll
        for (int off = 1; off < 64; off <<= 1) s += __shfl_xor(s, off, 64);
        if (lane == 0) {
            pl[row] = s;
            out_base[N_TOK * DIM + 1 + row] = (float)i;
        }
    }
}

// ---------------------------------------------------------------------------
// K4: reduce 8192 per-row loss partials -> loss = 1.25 * sum / (8*1024*256).
// ---------------------------------------------------------------------------
__global__ __launch_bounds__(1024) void finalize_loss(const float* __restrict__ pl,
                                                      float* __restrict__ out) {
    __shared__ float sw[16];
    const int t = threadIdx.x;
    float s = 0.f;
#pragma unroll
    for (int j = 0; j < 8; j++) s += pl[t + j * 1024];
#pragma unroll
    for (int off = 1; off < 64; off <<= 1) s += __shfl_xor(s, off, 64);
    if ((t & 63) == 0) sw[t >> 6] = s;
    __syncthreads();
    if (t < 16) {
        float v = sw[t];
#pragma unroll
        for (int off = 1; off < 16; off <<= 1) v += __shfl_xor(v, off, 64);
        if (t == 0) out[N_TOK * DIM] = v * (1.25f / 2097152.0f);
    }
}

// ---------------------------------------------------------------------------
extern "C" void kernel_launch(void* const* d_in, const int* in_sizes, int n_in,
                              void* d_out, int out_size, void* d_ws, size_t ws_size,
                              hipStream_t stream) {
    const float* z   = (const float*)d_in[0];   // [8,1024,256] fp32
    const float* emb = (const float*)d_in[1];   // [8192,256] fp32
    float* out = (float*)d_out;                 // z_q[2097152] | loss[1] | idx[8192]
    char* ws = (char*)d_ws;

    // ws layout (byte offsets; total ~33.6 MB)
    float*          en    = (float*)(ws);                      //  8 MiB fp32 codes (normalized)
    unsigned short* esw   = (unsigned short*)(ws + 8388608);   //  4 MiB bf16 codes (frag-swizzled)
    unsigned short* zb    = (unsigned short*)(ws + 12582912);  //  4 MiB bf16 z (plain row-major)
    float*          e2    = (float*)(ws + 16777216);           // 32 KiB ||e||^2
    unsigned short* segMh = (unsigned short*)(ws + 16809984);  // 16 MiB fp16 [8192][1024]
    float*          pl    = (float*)(ws + 33587200);           // 32 KiB per-row loss partials

    // 1) normalize both inputs (emb -> en/esw/e2; z -> d_out z_q region + zb)
    l2norm_all<<<(N_E + N_TOK) / 4, 256, 0, stream>>>(z, emb, out, zb, en, esw, e2);
    // 2) bf16 MFMA approx distances (R11 config: 128x128, BK=64 dbuf) -> fp16 mins
    mfma_dist<<<64 * 64, 256, 0, stream>>>(zb, esw, e2, segMh);
    // 3) fused select + exact rescore + gather (BLOCK per row, no global atomics)
    select_rescore<<<N_TOK, 256, 0, stream>>>(segMh, en, e2, out, out, pl);
    // 4) reduce loss partials
    finalize_loss<<<1, 1024, 0, stream>>>(pl, out);
}

// Round 14
// 139.117 us; speedup vs baseline: 1.0371x; 1.0371x over previous
//
#include <hip/hip_runtime.h>
#include <hip/hip_fp16.h>
#include <cfloat>
#include <math.h>

// Problem constants (fixed by the reference)
#define DIM    256
#define N_TOK  8192
#define N_E    8192
#define NSEG   1024         // 8-col groups per row
// Margin on d = ||e||^2 - 2*dot (bf16 approx pass, fp16-quantized group mins).
// Failure needs Dd(true)-Dd(approx-winner) + 2*quant > margin on a specific
// per-row pair: dot-err diff ~4.3sigma*6.8e-4 ~2.9e-3, fp16 quant 2*1e-3.
// 0.012 ~ 2.4x that. (Passed rounds 7-13; 0.016 and 0.008 also passed.)
#define MARGIN 0.012f

typedef __attribute__((ext_vector_type(8))) short bf16x8;
typedef __attribute__((ext_vector_type(4))) float f32x4;
typedef __attribute__((ext_vector_type(8))) unsigned short ushort8;

__device__ __forceinline__ unsigned short f2bf(float f) {      // RNE float->bf16
    unsigned u = __float_as_uint(f);
    unsigned r = u + 0x7fff + ((u >> 16) & 1);
    return (unsigned short)(r >> 16);
}
__device__ __forceinline__ unsigned fkey(float f) {            // monotone f32->u32
    unsigned u = __float_as_uint(f);
    return (u & 0x80000000u) ? ~u : (u | 0x80000000u);
}
__device__ __forceinline__ unsigned short f2h(float f) {       // RNE float->fp16 bits
    const __half h = __float2half(f);
    return *(const unsigned short*)&h;
}
__device__ __forceinline__ float h2f(unsigned short u) {
    __half_raw r; r.x = u;
    return __half2float((__half)r);
}

// ---------------------------------------------------------------------------
// K1: row-wise L2 normalize for BOTH inputs in one launch.
//  - z rows   -> zn fp32 (d_out scratch) + zb bf16 PLAIN row-major (the LDS
//    staging swizzle is applied via per-lane global addresses in mfma_dist).
//  - emb rows -> en fp32 + esw bf16 swizzled into exact MFMA A-fragment order
//    (frag16=row>>4, kc: 512 ushorts at (frag16*8+kc)*512; within:
//    ((k>>3&3)*16 + (row&15))*8 + (k&7)) + e2.
// ---------------------------------------------------------------------------
__global__ __launch_bounds__(256) void l2norm_all(const float* __restrict__ z,
                                                  const float* __restrict__ emb,
                                                  float* __restrict__ zn,
                                                  unsigned short* __restrict__ zb,
                                                  float* __restrict__ en,
                                                  unsigned short* __restrict__ esw,
                                                  float* __restrict__ e2) {
    const int lane = threadIdx.x & 63;
    const bool isE = blockIdx.x < (N_E / 4);
    const int row = (isE ? blockIdx.x : blockIdx.x - N_E / 4) * 4 + (threadIdx.x >> 6);
    const float* in = isE ? emb : z;
    float* out = isE ? en : zn;
    const float4 v = *(const float4*)(in + row * DIM + lane * 4);
    float s = v.x * v.x + v.y * v.y + v.z * v.z + v.w * v.w;
#pragma unroll
    for (int off = 1; off < 64; off <<= 1) s += __shfl_xor(s, off, 64);
    const float inv = 1.0f / fmaxf(sqrtf(s), 1e-12f);
    const float4 o = make_float4(v.x * inv, v.y * inv, v.z * inv, v.w * inv);
    *(float4*)(out + row * DIM + lane * 4) = o;
    ushort4 ob; ob.x = f2bf(o.x); ob.y = f2bf(o.y); ob.z = f2bf(o.z); ob.w = f2bf(o.w);
    const int k0 = lane * 4;
    if (isE) {
        const size_t sidx = ((size_t)((row >> 4) * 8 + (k0 >> 5)) * 64
                             + ((k0 >> 3) & 3) * 16 + (row & 15)) * 8 + (k0 & 7);
        *(ushort4*)(esw + sidx) = ob;
        float q = o.x * o.x + o.y * o.y + o.z * o.z + o.w * o.w;
#pragma unroll
        for (int off = 1; off < 64; off <<= 1) q += __shfl_xor(q, off, 64);
        if (lane == 0) e2[row] = q;
    } else {
        *(ushort4*)(zb + (size_t)row * DIM + k0) = ob;
    }
}

// ---------------------------------------------------------------------------
// K2: bf16 MFMA distance pass — R11 configuration (best measured: 49.1 us,
// MfmaUtil 27%, 0 bank conflicts) with occupancy raised to 3 blocks/CU
// (__launch_bounds__(256,3): unified reg need 68 VGPR + 64 AGPR = 132 <= 170;
// LDS 3 x 32 KB <= 160 KB). 128x128 tile, hybrid feed, BK=64 double-buffered
// z staging, 4 K-loop barriers/block.
// ---------------------------------------------------------------------------
__global__ __launch_bounds__(256, 3) void mfma_dist(const unsigned short* __restrict__ zb,
                                                    const unsigned short* __restrict__ esw,
                                                    const float* __restrict__ e2,
                                                    unsigned short* __restrict__ segMh) {
    __shared__ __align__(16) unsigned short As[2][128 * 64];   // 2 x 16 KB z chunk-pair
    float* sm = reinterpret_cast<float*>(As);                  // aliased epilogue [16][128]

    const int tid  = threadIdx.x;
    const int lane = tid & 63;
    const int wave = tid >> 6;
    const int wm = wave & 1, wn = wave >> 1;
    const int row0 = (blockIdx.x & 63) * 128;
    const int col0 = (blockIdx.x >> 6) * 128;
    const int fr = lane & 15, q = lane >> 4;

    f32x4 acc[4][4];
#pragma unroll
    for (int ci = 0; ci < 4; ci++)
#pragma unroll
        for (int zi = 0; zi < 4; zi++) acc[ci][zi] = (f32x4){0.f, 0.f, 0.f, 0.f};

    // Code fragments: frag16 group aBase+i, address = frag*4096 + kc*512 + lane*8
    const int aBase = (col0 >> 4) + wn * 4;
    auto la = [&](int i, int kc) {
        return *(const bf16x8*)(esw + (size_t)(aBase + i) * 4096 + kc * 512 + lane * 8);
    };
    // z staging, pair p (k in [p*64, p*64+64)): wave stages rows wave*32..+31,
    // 4 instrs of 1 KB; lane -> row lane>>3 of the 8-row slab, slot lane&7;
    // global chunk fetched = p*8 + (slot ^ (r&7)).
    const int cxor = (lane & 7) ^ ((lane >> 3) & 7);            // const per lane
    const unsigned short* gZ = zb + (size_t)(row0 + wave * 32 + (lane >> 3)) * DIM + cxor * 8;
    auto stage = [&](int buf, int p) {
#pragma unroll
        for (int j = 0; j < 4; j++) {
            __builtin_amdgcn_global_load_lds(
                (const __attribute__((address_space(1))) unsigned int*)(gZ + (size_t)j * 8 * DIM + p * 64),
                (__attribute__((address_space(3))) unsigned int*)&As[buf][(wave * 32 + j * 8) * 64],
                16, 0, 0);
        }
    };
    // z fragment from LDS: kc = 2p+h, logical chunk h*4+q, slot ^= (r&7).
    auto lz = [&](int buf, int i, int h) {
        const int r = wm * 64 + i * 16 + fr;
        const int slot = (h * 4 + q) ^ (fr & 7);
        return *(const bf16x8*)&As[buf][r * 64 + slot * 8];
    };

    bf16x8 ca[8][4];
#pragma unroll
    for (int i = 0; i < 4; i++) { ca[0][i] = la(i, 0); ca[1][i] = la(i, 1); }
    stage(0, 0);

#pragma unroll
    for (int p = 0; p < 4; p++) {
        __syncthreads();                 // drains stage(p) (2 kc of compute in flight)
        if (p < 3) stage((p + 1) & 1, p + 1);
#pragma unroll
        for (int h = 0; h < 2; h++) {
            const int kc = 2 * p + h;
            if (kc + 2 < 8) {
#pragma unroll
                for (int i = 0; i < 4; i++) ca[kc + 2][i] = la(i, kc + 2);
            }
            bf16x8 zfr[4];
#pragma unroll
            for (int i = 0; i < 4; i++) zfr[i] = lz(p & 1, i, h);
#pragma unroll
            for (int ci = 0; ci < 4; ci++)
#pragma unroll
                for (int zi = 0; zi < 4; zi++)
                    acc[ci][zi] = __builtin_amdgcn_mfma_f32_16x16x32_bf16(ca[kc][ci], zfr[zi], acc[ci][zi], 0, 0, 0);
        }
    }

    // Epilogue. C/D: m (code) = (lane>>4)*4 + reg, n (z row) = lane&15.
    float4 e2q[4];
#pragma unroll
    for (int ci = 0; ci < 4; ci++)
        e2q[ci] = *(const float4*)&e2[col0 + wn * 64 + ci * 16 + q * 4];
    __syncthreads();   // all As reads done; safe to reuse as sm
#pragma unroll
    for (int ci = 0; ci < 4; ci++) {
#pragma unroll
        for (int zi = 0; zi < 4; zi++) {
            const float t0 = fmaf(-2.0f, acc[ci][zi][0], e2q[ci].x);
            const float t1 = fmaf(-2.0f, acc[ci][zi][1], e2q[ci].y);
            const float t2 = fmaf(-2.0f, acc[ci][zi][2], e2q[ci].z);
            const float t3 = fmaf(-2.0f, acc[ci][zi][3], e2q[ci].w);
            float mm = fminf(fminf(t0, t1), fminf(t2, t3));   // min over 4 codes (regs)
            mm = fminf(mm, __shfl_xor(mm, 16, 64));           // pair quads: 8-code min
            // q==0 holds codes 0..7 min; q==2 holds codes 8..15 min
            if (q == 0) sm[(wn * 8 + ci * 2 + 0) * 128 + wm * 64 + zi * 16 + fr] = mm;
            if (q == 2) sm[(wn * 8 + ci * 2 + 1) * 128 + wm * 64 + zi * 16 + fr] = mm;
        }
    }
    __syncthreads();
    // Store 16 segs x 128 rows as fp16, coalesced: thread t -> row t&127,
    // 8 consecutive segs (part = t>>7).
    {
        const int rl = tid & 127, part = tid >> 7;
        ushort8 o8;
#pragma unroll
        for (int j = 0; j < 8; j++) o8[j] = f2h(sm[(part * 8 + j) * 128 + rl]);
        *(ushort8*)&segMh[(size_t)(row0 + rl) * NSEG + (col0 >> 3) + part * 8] = o8;
    }
}

// ---------------------------------------------------------------------------
// K3 (fused select+rescore+gather): one WAVE per row, ZERO global atomics,
// SOFTWARE-PIPELINED rescore.
//  1. read 1024 fp16 group-mins (2 KB contiguous), shuffle-min -> threshold
//  2. collect flagged segs (wave-uniform ballots) into a per-wave LDS list
//  3. 2-stage pipelined exact fp32 rescore: stage e+1's 8 float4 loads + e2
//     issue BEFORE stage e's shuffle-reduce, overlapping the L2 latency that
//     the old serial bit-walk exposed per group; packed (key|col) min ->
//     exact argmin with lowest-index tie-break (matches jnp.argmin).
//     Serial fallback beyond 8 flagged groups (never in practice) for rigor.
//  4. gather en[idx] -> z_q, per-row loss partial to pl[row], index out.
// ---------------------------------------------------------------------------
__global__ __launch_bounds__(256) void select_rescore(const unsigned short* __restrict__ segMh,
                                                      const float* __restrict__ en,
                                                      const float* __restrict__ e2,
                                                      float* zq,        // d_out: z_norm in / z_q out
                                                      float* out_base,  // d_out
                                                      float* __restrict__ pl) {
    __shared__ unsigned short s_segs[4][8];
    const int lane = threadIdx.x & 63;
    const int wv   = threadIdx.x >> 6;
    const int row  = (blockIdx.x << 2) + wv;
    const unsigned short* ph = segMh + (size_t)row * NSEG + lane * 16;
    const ushort8 u0 = *(const ushort8*)ph;
    const ushort8 u1 = *(const ushort8*)(ph + 8);
    float vv[16];
#pragma unroll
    for (int j = 0; j < 8; j++) { vv[j] = h2f(u0[j]); vv[8 + j] = h2f(u1[j]); }
    float m = vv[0];
#pragma unroll
    for (int j = 1; j < 16; j++) m = fminf(m, vv[j]);
#pragma unroll
    for (int off = 1; off < 64; off <<= 1) m = fminf(m, __shfl_xor(m, off, 64));
    const float thr = m + MARGIN;

    // Collect flagged segs (wave-uniform) into the per-wave LDS list.
    int F = 0;
#pragma unroll
    for (int j = 0; j < 16; j++) {
        unsigned long long bal = __ballot(vv[j] <= thr);
        while (bal) {
            const int l = __ffsll(bal) - 1;
            bal &= bal - 1;
            if (F < 8 && lane == 0) s_segs[wv][F] = (unsigned short)(l * 16 + j);
            F++;
        }
    }
    const int n = (F < 8) ? F : 8;

    // z row in 16-lane-split layout for the rescore dots (shared by all groups)
    const int q = lane >> 4, f = lane & 15;
    const float4* zp = (const float4*)(zq + (size_t)row * DIM);
    float4 z4[4];
#pragma unroll
    for (int j = 0; j < 4; j++) z4[j] = zp[j * 16 + f];

    unsigned long long pk = ~0ull;
    auto doload = [&](float4 (&ev)[2][4], float (&ee)[2], int seg) {
#pragma unroll
        for (int g = 0; g < 2; g++) {
            const int col = seg * 8 + g * 4 + q;
            const float4* ep = (const float4*)(en + (size_t)col * DIM);
#pragma unroll
            for (int jj = 0; jj < 4; jj++) ev[g][jj] = ep[jj * 16 + f];
            ee[g] = e2[col];
        }
    };
    auto dorescore = [&](const float4 (&ev)[2][4], const float (&ee)[2], int seg) {
#pragma unroll
        for (int g = 0; g < 2; g++) {
            float s = 0.f;
#pragma unroll
            for (int jj = 0; jj < 4; jj++) {
                s = fmaf(z4[jj].x, ev[g][jj].x, s); s = fmaf(z4[jj].y, ev[g][jj].y, s);
                s = fmaf(z4[jj].z, ev[g][jj].z, s); s = fmaf(z4[jj].w, ev[g][jj].w, s);
            }
#pragma unroll
            for (int off = 1; off < 16; off <<= 1) s += __shfl_xor(s, off, 64);
            const float d = fmaf(-2.0f, s, ee[g]);
            const int col = seg * 8 + g * 4 + q;
            const unsigned long long key =
                ((unsigned long long)fkey(d) << 32) | (unsigned)col;
            if (key < pk) pk = key;
        }
    };

    float4 evA[2][4], evB[2][4];
    float eA[2], eB[2];
    int sgA = s_segs[wv][0], sgB = 0;
    doload(evA, eA, sgA);
#pragma unroll
    for (int e = 0; e < 8; e++) {
        if (e >= n) break;
        if ((e & 1) == 0) {
            if (e + 1 < n) { sgB = s_segs[wv][e + 1]; doload(evB, eB, sgB); }
            dorescore(evA, eA, sgA);
        } else {
            if (e + 1 < n) { sgA = s_segs[wv][e + 1]; doload(evA, eA, sgA); }
            dorescore(evB, eB, sgB);
        }
    }
    if (F > 8) {                       // exactness fallback (practically never)
        int c = 0;
#pragma unroll
        for (int j = 0; j < 16; j++) {
            unsigned long long bal = __ballot(vv[j] <= thr);
            while (bal) {
                const int l = __ffsll(bal) - 1;
                bal &= bal - 1;
                if (c >= 8) {
                    const int seg = l * 16 + j;
                    float4 evT[2][4]; float eT[2];
                    doload(evT, eT, seg);
                    dorescore(evT, eT, seg);
                }
                c++;
            }
        }
    }
#pragma unroll
    for (int off = 16; off < 64; off <<= 1) {               // merge the 4 quads
        const unsigned long long o = __shfl_xor(pk, off, 64);
        if (o < pk) pk = o;
    }
    const int i = (int)(pk & 0xffffffffu);

    // Gather z_q, loss partial, index (plain stores, no atomics).
    const float4 qv = *(const float4*)(en + (size_t)i * DIM + lane * 4);
    const float4 zv = *(const float4*)(zq + (size_t)row * DIM + lane * 4);
    const float dx = qv.x - zv.x, dy = qv.y - zv.y, dz = qv.z - zv.z, dw = qv.w - zv.w;
    float s = dx * dx + dy * dy + dz * dz + dw * dw;
    *(float4*)(zq + (size_t)row * DIM + lane * 4) = qv;
#pragma unroll
    for (int off = 1; off < 64; off <<= 1) s += __shfl_xor(s, off, 64);
    if (lane == 0) {
        pl[row] = s;
        out_base[N_TOK * DIM + 1 + row] = (float)i;
    }
}

// ---------------------------------------------------------------------------
// K4: reduce 8192 per-row loss partials -> loss = 1.25 * sum / (8*1024*256).
// ---------------------------------------------------------------------------
__global__ __launch_bounds__(1024) void finalize_loss(const float* __restrict__ pl,
                                                      float* __restrict__ out) {
    __shared__ float sw[16];
    const int t = threadIdx.x;
    float s = 0.f;
#pragma unroll
    for (int j = 0; j < 8; j++) s += pl[t + j * 1024];
#pragma unroll
    for (int off = 1; off < 64; off <<= 1) s += __shfl_xor(s, off, 64);
    if ((t & 63) == 0) sw[t >> 6] = s;
    __syncthreads();
    if (t < 16) {
        float v = sw[t];
#pragma unroll
        for (int off = 1; off < 16; off <<= 1) v += __shfl_xor(v, off, 64);
        if (t == 0) out[N_TOK * DIM] = v * (1.25f / 2097152.0f);
    }
}

// ---------------------------------------------------------------------------
extern "C" void kernel_launch(void* const* d_in, const int* in_sizes, int n_in,
                              void* d_out, int out_size, void* d_ws, size_t ws_size,
                              hipStream_t stream) {
    const float* z   = (const float*)d_in[0];   // [8,1024,256] fp32
    const float* emb = (const float*)d_in[1];   // [8192,256] fp32
    float* out = (float*)d_out;                 // z_q[2097152] | loss[1] | idx[8192]
    char* ws = (char*)d_ws;

    // ws layout (byte offsets; total ~33.6 MB)
    float*          en    = (float*)(ws);                      //  8 MiB fp32 codes (normalized)
    unsigned short* esw   = (unsigned short*)(ws + 8388608);   //  4 MiB bf16 codes (frag-swizzled)
    unsigned short* zb    = (unsigned short*)(ws + 12582912);  //  4 MiB bf16 z (plain row-major)
    float*          e2    = (float*)(ws + 16777216);           // 32 KiB ||e||^2
    unsigned short* segMh = (unsigned short*)(ws + 16809984);  // 16 MiB fp16 [8192][1024]
    float*          pl    = (float*)(ws + 33587200);           // 32 KiB per-row loss partials

    // 1) normalize both inputs (emb -> en/esw/e2; z -> d_out z_q region + zb)
    l2norm_all<<<(N_E + N_TOK) / 4, 256, 0, stream>>>(z, emb, out, zb, en, esw, e2);
    // 2) bf16 MFMA approx distances (R11 config, 3 blocks/CU) -> fp16 mins
    mfma_dist<<<64 * 64, 256, 0, stream>>>(zb, esw, e2, segMh);
    // 3) fused select + pipelined exact rescore + gather (wave per row)
    select_rescore<<<N_TOK / 4, 256, 0, stream>>>(segMh, en, e2, out, out, pl);
    // 4) reduce loss partials
    finalize_loss<<<1, 1024, 0, stream>>>(pl, out);
}